// Round 1
// baseline (12934.422 us; speedup 1.0000x reference)
//
#include <hip/hip_runtime.h>
#include <math.h>

// RNN greedy decoder: 32 steps x (embed -> 4 LSTM layers -> emb proj -> logits -> softmax/argmax)
// fp32 everywhere: argmax feedback needs ~1e-6 logit fidelity vs numpy fp32 ref.
// This round: (1) fused front kernel (4 LSTM layers + emb) -- 5 launches -> 1,
//             (2) softmax normalize deferred out of the sequential loop (single pass at end).
#define T_STEPS 32
#define B 256
#define H 128
#define NL 4
#define V 32000
#define G4 (4*H)        // 512 gates per layer
#define VT 64
#define VTILES (V/VT)   // 500

// ---------------- init: copy h,c into ws, prev = eos ----------------
__global__ void k_init(const float* __restrict__ hidden, const float* __restrict__ cell,
                       const int* __restrict__ eos,
                       float* __restrict__ h_a, float* __restrict__ cbuf, int* __restrict__ prev)
{
    int i = blockIdx.x * blockDim.x + threadIdx.x;
    int n = NL * B * H;
    if (i < n) { h_a[i] = hidden[i]; cbuf[i] = cell[i]; }
    if (i < B) prev[i] = eos[0];
}

// ---------------- fused front: embed gather + 4 LSTM layers + emb projection ----------------
// grid: 64 blocks (batch tiles of 4), 512 threads.
// Per thread: one (batch row r, col) pair, 4 gates -> identical inner loop / fp32
// accumulation order to the previous verified per-layer kernel.
// Wave w = tid>>6 owns col tile [w*16, w*16+16): each wave streams exactly its own
// 64KB weight slice per layer (no cross-wave redundancy).
__global__ __launch_bounds__(512) void k_front(
    const float* __restrict__ W_in, const float* __restrict__ b_in,
    const int* __restrict__ prev,
    const float* __restrict__ Wih_all, const float* __restrict__ Whh_all,
    const float* __restrict__ bih_all, const float* __restrict__ bhh_all,
    const float* __restrict__ h_read, float* __restrict__ h_write,
    float* __restrict__ c_io,
    const float* __restrict__ W_re, const float* __restrict__ b_re,
    float* __restrict__ emb)
{
    __shared__ float bufA[4][132];   // x ping
    __shared__ float bufB[4][132];   // x pong
    __shared__ float hs[4][132];     // recurrent h for current layer
    int tid = threadIdx.x;
    int b0 = blockIdx.x * 4;

    // x0 = W_in[prev[b]] + b_in   (4 rows x 32 float4 = 128 slots)
    if (tid < 128) {
        int row = tid >> 5, c4 = (tid & 31) << 2;
        int tok = prev[b0 + row];
        float4 xv = *(const float4*)&W_in[(size_t)tok * H + c4];
        float4 bv = *(const float4*)&b_in[c4];
        xv.x += bv.x; xv.y += bv.y; xv.z += bv.z; xv.w += bv.w;
        *(float4*)&bufA[row][c4] = xv;
    }

    int jj  = tid & 15;          // col within wave tile
    int r   = (tid >> 4) & 3;    // batch row within tile
    int w   = tid >> 6;          // wave -> col tile
    int col = w * 16 + jj;       // 0..127

    float (*xc)[132] = bufA;     // x for current layer
    float (*xn)[132] = bufB;     // h output -> next layer's x

    for (int l = 0; l < NL; l++) {
        if (tid < 128) {
            int row = tid >> 5, c4 = (tid & 31) << 2;
            *(float4*)&hs[row][c4] =
                *(const float4*)&h_read[(size_t)l * B * H + (size_t)(b0 + row) * H + c4];
        }
        __syncthreads();   // hs + xc ready

        const float* Wih = Wih_all + (size_t)l * G4 * H;
        const float* Whh = Whh_all + (size_t)l * G4 * H;
        const float* bih = bih_all + (size_t)l * G4;
        const float* bhh = bhh_all + (size_t)l * G4;

        float acc[4];
#pragma unroll
        for (int q = 0; q < 4; q++) acc[q] = bih[q * 128 + col] + bhh[q * 128 + col];

        const float4* xr  = (const float4*)&xc[r][0];
        const float4* hr  = (const float4*)&hs[r][0];
        const float4* wi0 = (const float4*)(Wih + (size_t)col * H);
        const float4* wh0 = (const float4*)(Whh + (size_t)col * H);
#pragma unroll 4
        for (int k4 = 0; k4 < 32; k4++) {
            float4 xv = xr[k4];
            float4 hv = hr[k4];
#pragma unroll
            for (int q = 0; q < 4; q++) {
                float4 wiv = wi0[q * 128 * 32 + k4];   // row q*128+col
                float4 whv = wh0[q * 128 * 32 + k4];
                acc[q] += xv.x * wiv.x + xv.y * wiv.y + xv.z * wiv.z + xv.w * wiv.w
                        + hv.x * whv.x + hv.y * whv.y + hv.z * whv.z + hv.w * whv.w;
            }
        }

        // torch gate order: i, f, g, o
        float si = 1.f / (1.f + expf(-acc[0]));
        float sf = 1.f / (1.f + expf(-acc[1]));
        float tg = tanhf(acc[2]);
        float so = 1.f / (1.f + expf(-acc[3]));
        size_t idx = (size_t)l * B * H + (size_t)(b0 + r) * H + col;
        float cn = sf * c_io[idx] + si * tg;
        c_io[idx] = cn;
        float hn = so * tanhf(cn);
        h_write[idx] = hn;      // for next time step
        xn[r][col] = hn;        // for next layer
        __syncthreads();        // all reads of xc/hs done before next layer overwrites
        float (*tmp)[132] = xc; xc = xn; xn = tmp;
    }

    // emb = h3 @ W_re.T + b_re  (same accumulation order as old k_emb)
    float acc = b_re[col];
    const float4* hr3 = (const float4*)&xc[r][0];
    const float4* wr  = (const float4*)(W_re + (size_t)col * H);
#pragma unroll 8
    for (int k4 = 0; k4 < 32; k4++) {
        float4 hv = hr3[k4];
        float4 wv = wr[k4];
        acc += hv.x * wv.x + hv.y * wv.y + hv.z * wv.z + hv.w * wv.w;
    }
    emb[(size_t)(b0 + r) * H + col] = acc;
}

// ---------------- logits tile + softmax partials (UNCHANGED, verified) ----------------
// grid: x = 500 vocab tiles of 64, y = 4 batch tiles of 64; 256 threads
// writes raw logits into out_t, plus per-(row,tile) max/argmax/sumexp partials.
__global__ __launch_bounds__(256) void k_logits(
    const float* __restrict__ emb, const float* __restrict__ Wlo,
    const float* __restrict__ blo, float* __restrict__ out_t,
    float* __restrict__ pmax, float* __restrict__ psum, int* __restrict__ pidx)
{
    __shared__ float es[64][132];
    __shared__ float red_f[64][16];
    __shared__ int   red_i[64][16];
    __shared__ float rowM[64];

    int tid = threadIdx.x;
    int b0 = blockIdx.y * 64;
    int v0 = blockIdx.x * VT;

    for (int i = tid; i < 2048; i += 256) {      // 64 rows x 32 float4
        int row = i >> 5, c4 = (i & 31) << 2;
        *(float4*)&es[row][c4] = *(const float4*)&emb[(b0 + row) * H + c4];
    }
    __syncthreads();

    int tb = tid >> 4;   // 0..15 -> rows 4*tb..+3
    int tv = tid & 15;   // 0..15 -> cols v0+4*tv..+3
    float acc[4][4];
#pragma unroll
    for (int a = 0; a < 4; a++)
#pragma unroll
        for (int b = 0; b < 4; b++) acc[a][b] = 0.f;

    const float4* wp0 = (const float4*)(Wlo + (size_t)(v0 + 4 * tv + 0) * H);
    const float4* wp1 = (const float4*)(Wlo + (size_t)(v0 + 4 * tv + 1) * H);
    const float4* wp2 = (const float4*)(Wlo + (size_t)(v0 + 4 * tv + 2) * H);
    const float4* wp3 = (const float4*)(Wlo + (size_t)(v0 + 4 * tv + 3) * H);
    const float4* e0 = (const float4*)&es[4 * tb + 0][0];
    const float4* e1 = (const float4*)&es[4 * tb + 1][0];
    const float4* e2 = (const float4*)&es[4 * tb + 2][0];
    const float4* e3 = (const float4*)&es[4 * tb + 3][0];

#pragma unroll 2
    for (int k4 = 0; k4 < 32; k4++) {
        float4 ev[4] = { e0[k4], e1[k4], e2[k4], e3[k4] };
        float4 wv[4] = { wp0[k4], wp1[k4], wp2[k4], wp3[k4] };
#pragma unroll
        for (int a = 0; a < 4; a++)
#pragma unroll
            for (int b = 0; b < 4; b++)
                acc[a][b] += ev[a].x * wv[b].x + ev[a].y * wv[b].y
                           + ev[a].z * wv[b].z + ev[a].w * wv[b].w;
    }

    float bl[4];
#pragma unroll
    for (int b = 0; b < 4; b++) bl[b] = blo[v0 + 4 * tv + b];

#pragma unroll
    for (int a = 0; a < 4; a++) {
        int row = 4 * tb + a;
        float4 st;
        st.x = acc[a][0] + bl[0];
        st.y = acc[a][1] + bl[1];
        st.z = acc[a][2] + bl[2];
        st.w = acc[a][3] + bl[3];
        acc[a][0] = st.x; acc[a][1] = st.y; acc[a][2] = st.z; acc[a][3] = st.w;
        *(float4*)&out_t[(size_t)(b0 + row) * V + v0 + 4 * tv] = st;
    }

    // per-row partial max/argmax within this 64-col tile
#pragma unroll
    for (int a = 0; a < 4; a++) {
        int row = 4 * tb + a;
        float m = acc[a][0]; int mi = v0 + 4 * tv;
#pragma unroll
        for (int b = 1; b < 4; b++)
            if (acc[a][b] > m) { m = acc[a][b]; mi = v0 + 4 * tv + b; }
        red_f[row][tv] = m;
        red_i[row][tv] = mi;
    }
    __syncthreads();
    if (tid < 64) {
        float m = red_f[tid][0]; int mi = red_i[tid][0];
        for (int j = 1; j < 16; j++) {
            float f = red_f[tid][j]; int ix = red_i[tid][j];
            if (f > m || (f == m && ix < mi)) { m = f; mi = ix; }
        }
        rowM[tid] = m;
        pmax[(size_t)(b0 + tid) * VTILES + blockIdx.x] = m;
        pidx[(size_t)(b0 + tid) * VTILES + blockIdx.x] = mi;
    }
    __syncthreads();
#pragma unroll
    for (int a = 0; a < 4; a++) {
        int row = 4 * tb + a;
        float M = rowM[row];
        float s = expf(acc[a][0] - M) + expf(acc[a][1] - M)
                + expf(acc[a][2] - M) + expf(acc[a][3] - M);
        red_f[row][tv] = s;
    }
    __syncthreads();
    if (tid < 64) {
        float s = 0.f;
        for (int j = 0; j < 16; j++) s += red_f[tid][j];
        psum[(size_t)(b0 + tid) * VTILES + blockIdx.x] = s;
    }
}

// ---------------- combine partials: argmax->prev, store M and 1/Z (no normalize) ----------------
__global__ __launch_bounds__(256) void k_stats(
    const float* __restrict__ pmax, const float* __restrict__ psum,
    const int* __restrict__ pidx,
    int* __restrict__ prev, float* __restrict__ Mout, float* __restrict__ iZout)
{
    int b = blockIdx.x, tid = threadIdx.x;
    __shared__ float wm[4]; __shared__ int wi[4];
    __shared__ float sM; __shared__ int sI;

    float M = -1e30f; int I = 0x7fffffff;
    for (int i = tid; i < VTILES; i += 256) {
        float m = pmax[(size_t)b * VTILES + i];
        int  ix = pidx[(size_t)b * VTILES + i];
        if (m > M || (m == M && ix < I)) { M = m; I = ix; }
    }
    for (int off = 32; off; off >>= 1) {
        float m2 = __shfl_down(M, off);
        int  i2 = __shfl_down(I, off);
        if (m2 > M || (m2 == M && i2 < I)) { M = m2; I = i2; }
    }
    int wid = tid >> 6, lane = tid & 63;
    if (lane == 0) { wm[wid] = M; wi[wid] = I; }
    __syncthreads();
    if (tid == 0) {
        M = wm[0]; I = wi[0];
        for (int q = 1; q < 4; q++)
            if (wm[q] > M || (wm[q] == M && wi[q] < I)) { M = wm[q]; I = wi[q]; }
        sM = M; sI = I;
    }
    __syncthreads();
    M = sM;

    float z = 0.f;
    for (int i = tid; i < VTILES; i += 256)
        z += psum[(size_t)b * VTILES + i] * expf(pmax[(size_t)b * VTILES + i] - M);
    for (int off = 32; off; off >>= 1) z += __shfl_down(z, off);
    if (lane == 0) wm[wid] = z;
    __syncthreads();
    if (tid == 0) {
        float sZ = wm[0] + wm[1] + wm[2] + wm[3];
        prev[b] = sI;
        Mout[b] = M;
        iZout[b] = 1.f / sZ;
    }
}

// ---------------- final normalize pass over all 32 steps (streaming, HBM-bound) ----------------
// grid: 8192 blocks = one per (t,b) row; Mbuf/iZbuf laid out [t][b] so blockIdx maps directly.
__global__ __launch_bounds__(256) void k_norm(
    float* __restrict__ out, const float* __restrict__ Mbuf,
    const float* __restrict__ iZbuf)
{
    int bid = blockIdx.x;            // t = bid>>8, b = bid&255
    float M  = Mbuf[bid];
    float iZ = iZbuf[bid];
    float4* row = (float4*)(out + (size_t)bid * V);
    for (int i = threadIdx.x; i < V / 4; i += 256) {
        float4 lv = row[i];
        float4 p;
        p.x = expf(lv.x - M) * iZ;
        p.y = expf(lv.y - M) * iZ;
        p.z = expf(lv.z - M) * iZ;
        p.w = expf(lv.w - M) * iZ;
        row[i] = p;
    }
}

extern "C" void kernel_launch(void* const* d_in, const int* in_sizes, int n_in,
                              void* d_out, int out_size, void* d_ws, size_t ws_size,
                              hipStream_t stream)
{
    const float* hidden = (const float*)d_in[0];
    const float* cell   = (const float*)d_in[1];
    const float* W_in   = (const float*)d_in[2];
    const float* b_in   = (const float*)d_in[3];
    const float* W_ih   = (const float*)d_in[4];
    const float* W_hh   = (const float*)d_in[5];
    const float* b_ih   = (const float*)d_in[6];
    const float* b_hh   = (const float*)d_in[7];
    const float* W_re   = (const float*)d_in[8];
    const float* b_re   = (const float*)d_in[9];
    const float* W_lo   = (const float*)d_in[10];
    const float* b_lo   = (const float*)d_in[11];
    const int*   eos    = (const int*)d_in[12];
    float* out = (float*)d_out;
    float* ws  = (float*)d_ws;

    // ws layout (floats): ~3.31 MB
    float* h_a  = ws;                        // 4*256*128
    float* h_b  = ws + 131072;
    float* cbuf = ws + 262144;
    float* emb  = ws + 393216;               // 256*128
    float* pmax = ws + 425984;               // 256*500
    float* psum = ws + 553984;
    int*   pidx = (int*)(ws + 681984);
    int*   prev = (int*)(ws + 809984);       // 256 ints
    float* Mbuf = ws + 810240;               // 32*256
    float* iZbuf= ws + 818432;               // 32*256

    k_init<<<512, 256, 0, stream>>>(hidden, cell, eos, h_a, cbuf, prev);

    for (int t = 0; t < T_STEPS; t++) {
        float* hr = (t & 1) ? h_b : h_a;   // read buffer (prev step's h)
        float* hw = (t & 1) ? h_a : h_b;   // write buffer (this step's h)
        k_front<<<64, 512, 0, stream>>>(
            W_in, b_in, prev,
            W_ih, W_hh, b_ih, b_hh,
            hr, hw, cbuf,
            W_re, b_re, emb);
        float* out_t = out + (size_t)t * B * V;
        k_logits<<<dim3(VTILES, 4), 256, 0, stream>>>(emb, W_lo, b_lo, out_t, pmax, psum, pidx);
        k_stats<<<256, 256, 0, stream>>>(pmax, psum, pidx, prev,
                                         Mbuf + t * 256, iZbuf + t * 256);
    }
    k_norm<<<8192, 256, 0, stream>>>(out, Mbuf, iZbuf);
}